// Round 1
// baseline (622.790 us; speedup 1.0000x reference)
//
#include <hip/hip_runtime.h>

#define NGRAPHS 256

// ---------------- degree / normalization ----------------

__global__ void k_deg(const int* __restrict__ dst, int E, int* __restrict__ deg) {
    int e = blockIdx.x * blockDim.x + threadIdx.x;
    int stride = gridDim.x * blockDim.x;
    for (; e < E; e += stride) atomicAdd(&deg[dst[e]], 1);
}

__global__ void k_dis(const int* __restrict__ deg, float* __restrict__ dis, int N) {
    int i = blockIdx.x * blockDim.x + threadIdx.x;
    if (i < N) dis[i] = rsqrtf((float)deg[i] + 1.0f);
}

// ---------------- exclusive scan (3 kernels) ----------------

__global__ void k_scanA(const int* __restrict__ deg, int N,
                        int* __restrict__ incl, int* __restrict__ bsum) {
    __shared__ int s[256];
    int t = threadIdx.x;
    int i = blockIdx.x * 256 + t;
    int v = (i < N) ? deg[i] : 0;
    s[t] = v;
    __syncthreads();
    for (int o = 1; o < 256; o <<= 1) {
        int add = (t >= o) ? s[t - o] : 0;
        __syncthreads();
        s[t] += add;
        __syncthreads();
    }
    if (i < N) incl[i] = s[t];
    if (t == 255) bsum[blockIdx.x] = s[255];
}

__global__ void k_scanB(int* __restrict__ bsum, int NB) {
    __shared__ int s[512];
    int t = threadIdx.x;
    s[t] = (t < NB) ? bsum[t] : 0;
    __syncthreads();
    for (int o = 1; o < 512; o <<= 1) {
        int add = (t >= o) ? s[t - o] : 0;
        __syncthreads();
        s[t] += add;
        __syncthreads();
    }
    if (t < NB) bsum[t] = (t == 0) ? 0 : s[t - 1];   // exclusive block offsets
}

__global__ void k_scanC(const int* __restrict__ deg, const int* __restrict__ incl,
                        const int* __restrict__ boff, int N, int E,
                        int* __restrict__ row_start, int* __restrict__ cursor) {
    int i = blockIdx.x * 256 + threadIdx.x;
    if (i < N) {
        int ex = incl[i] - deg[i] + boff[blockIdx.x];
        row_start[i] = ex;
        cursor[i] = ex;
    }
    if (i == 0) row_start[N] = E;
}

__global__ void k_scatter(const int* __restrict__ src, const int* __restrict__ dst, int E,
                          int* __restrict__ cursor, int* __restrict__ csr_src) {
    int e = blockIdx.x * blockDim.x + threadIdx.x;
    int stride = gridDim.x * blockDim.x;
    for (; e < E; e += stride) {
        int pos = atomicAdd(&cursor[dst[e]], 1);
        csr_src[pos] = src[e];
    }
}

// ---------------- dense GEMM: H = X @ W  (X [N,64], W [64,64]) ----------------

__global__ __launch_bounds__(256) void k_gemm64(const float* __restrict__ X,
                                                const float* __restrict__ W,
                                                float* __restrict__ H, int N) {
    __shared__ float ws[64 * 64];
    __shared__ float xs[64 * 64];
    int t = threadIdx.x;
    int row0 = blockIdx.x * 64;
    int nr = N - row0; if (nr > 64) nr = 64;

    // stage W (4096 f32 = 1024 float4)
    const float4* W4 = (const float4*)W;
    float4* ws4 = (float4*)ws;
    for (int i = t; i < 1024; i += 256) ws4[i] = W4[i];
    // stage X tile (full rows only)
    const float4* X4 = (const float4*)(X + (size_t)row0 * 64);
    float4* xs4 = (float4*)xs;
    for (int i = t; i < nr * 16; i += 256) xs4[i] = X4[i];
    __syncthreads();

    int col = t & 63;
    int rg  = t >> 6;           // wave id: rows rg*16 .. rg*16+15
    float acc[16];
#pragma unroll
    for (int j = 0; j < 16; ++j) acc[j] = 0.0f;

    for (int k4 = 0; k4 < 16; ++k4) {
        float w0 = ws[(k4 * 4 + 0) * 64 + col];
        float w1 = ws[(k4 * 4 + 1) * 64 + col];
        float w2 = ws[(k4 * 4 + 2) * 64 + col];
        float w3 = ws[(k4 * 4 + 3) * 64 + col];
#pragma unroll
        for (int j = 0; j < 16; ++j) {
            float4 xv = xs4[(rg * 16 + j) * 16 + k4];   // wave-uniform broadcast
            acc[j] = fmaf(xv.x, w0, acc[j]);
            acc[j] = fmaf(xv.y, w1, acc[j]);
            acc[j] = fmaf(xv.z, w2, acc[j]);
            acc[j] = fmaf(xv.w, w3, acc[j]);
        }
    }
#pragma unroll
    for (int j = 0; j < 16; ++j) {
        int r = rg * 16 + j;
        if (r < nr) H[(size_t)(row0 + r) * 64 + col] = acc[j];
    }
}

// ---------------- aggregation: one wave per node, lane = feature ----------------

template <bool RELU>
__global__ __launch_bounds__(256) void k_agg(const float* __restrict__ h,
                                             const float* __restrict__ dis,
                                             const int* __restrict__ row_start,
                                             const int* __restrict__ csr_src,
                                             const float* __restrict__ b,
                                             float* __restrict__ out, int N) {
    int wid = (blockIdx.x * blockDim.x + threadIdx.x) >> 6;  // node id
    int lane = threadIdx.x & 63;
    if (wid >= N) return;
    int beg = row_start[wid];
    int end = row_start[wid + 1];
    float acc = 0.0f;
    int e = beg;
    for (; e + 2 <= end; e += 2) {
        int s0 = csr_src[e];
        int s1 = csr_src[e + 1];
        float d0 = dis[s0];
        float d1 = dis[s1];
        float h0 = h[(size_t)s0 * 64 + lane];
        float h1 = h[(size_t)s1 * 64 + lane];
        acc = fmaf(h0, d0, acc);
        acc = fmaf(h1, d1, acc);
    }
    if (e < end) {
        int s0 = csr_src[e];
        acc = fmaf(h[(size_t)s0 * 64 + lane], dis[s0], acc);
    }
    float d = dis[wid];
    float v = fmaf(acc, d, h[(size_t)wid * 64 + lane] * (d * d)) + b[lane];
    if (RELU) v = fmaxf(v, 0.0f);
    out[(size_t)wid * 64 + lane] = v;
}

// ---------------- pooling: block per graph, sorted batch binary search ----------------

__global__ __launch_bounds__(256) void k_pool(const float* __restrict__ h,
                                              const int* __restrict__ batch,
                                              const float* __restrict__ Wl,
                                              const float* __restrict__ bl,
                                              float* __restrict__ out, int N) {
    int g = blockIdx.x;
    // lower bound
    int lo = 0, hi = N;
    while (lo < hi) { int m = (lo + hi) >> 1; if (batch[m] < g) lo = m + 1; else hi = m; }
    int start = lo;
    // upper bound
    hi = N;
    while (lo < hi) { int m = (lo + hi) >> 1; if (batch[m] <= g) lo = m + 1; else hi = m; }
    int end = lo;

    int lane = threadIdx.x & 63;
    int wv = threadIdx.x >> 6;
    float part = 0.0f;
    for (int i = start + wv; i < end; i += 4)
        part += h[(size_t)i * 64 + lane];
    part *= Wl[lane];
    for (int o = 32; o; o >>= 1) part += __shfl_down(part, o);
    __shared__ float ps[4];
    if (lane == 0) ps[wv] = part;
    __syncthreads();
    if (threadIdx.x == 0) {
        float s = ps[0] + ps[1] + ps[2] + ps[3];
        float cnt = (float)(end - start);
        out[g] = s / fmaxf(cnt, 1.0f) + bl[0];
    }
}

// ---------------- launcher ----------------

extern "C" void kernel_launch(void* const* d_in, const int* in_sizes, int n_in,
                              void* d_out, int out_size, void* d_ws, size_t ws_size,
                              hipStream_t stream) {
    const float* x     = (const float*)d_in[0];
    const int*   ei    = (const int*)d_in[1];
    const int*   batch = (const int*)d_in[2];
    const float* W1 = (const float*)d_in[3];
    const float* b1 = (const float*)d_in[4];
    const float* W2 = (const float*)d_in[5];
    const float* b2 = (const float*)d_in[6];
    const float* W3 = (const float*)d_in[7];
    const float* b3 = (const float*)d_in[8];
    const float* Wl = (const float*)d_in[9];
    const float* bl = (const float*)d_in[10];
    float* out = (float*)d_out;

    const int N = in_sizes[0] / 64;
    const int E = in_sizes[1] / 2;
    const int* src = ei;
    const int* dst = ei + E;

    char* w = (char*)d_ws;
    auto alloc = [&](size_t bytes) -> void* {
        void* p = (void*)w;
        w += (bytes + 255) & ~(size_t)255;
        return p;
    };
    float* hA        = (float*)alloc((size_t)N * 64 * 4);
    float* hB        = (float*)alloc((size_t)N * 64 * 4);
    int*   csr       = (int*)alloc((size_t)E * 4);
    int*   deg       = (int*)alloc((size_t)N * 4);
    float* dis       = (float*)alloc((size_t)N * 4);
    int*   incl      = (int*)alloc((size_t)N * 4);
    int*   row_start = (int*)alloc((size_t)(N + 1) * 4);
    int*   cursor    = (int*)alloc((size_t)N * 4);
    int*   bsum      = (int*)alloc((size_t)512 * 4);

    hipMemsetAsync(deg, 0, (size_t)N * 4, stream);

    int eb = (E + 255) / 256; if (eb > 2048) eb = 2048;
    int nb = (N + 255) / 256;   // 391 for N=100000, fits k_scanB's 512

    k_deg<<<eb, 256, 0, stream>>>(dst, E, deg);
    k_dis<<<nb, 256, 0, stream>>>(deg, dis, N);
    k_scanA<<<nb, 256, 0, stream>>>(deg, N, incl, bsum);
    k_scanB<<<1, 512, 0, stream>>>(bsum, nb);
    k_scanC<<<nb, 256, 0, stream>>>(deg, incl, bsum, N, E, row_start, cursor);
    k_scatter<<<eb, 256, 0, stream>>>(src, dst, E, cursor, csr);

    int gb = (N + 63) / 64;     // gemm blocks
    int ab = (N + 3) / 4;       // agg blocks (4 waves/block, wave per node)

    // layer 1: relu(gcn(x, W1, b1))
    k_gemm64<<<gb, 256, 0, stream>>>(x, W1, hA, N);
    k_agg<true><<<ab, 256, 0, stream>>>(hA, dis, row_start, csr, b1, hB, N);
    // layer 2
    k_gemm64<<<gb, 256, 0, stream>>>(hB, W2, hA, N);
    k_agg<true><<<ab, 256, 0, stream>>>(hA, dis, row_start, csr, b2, hB, N);
    // layer 3 (no relu)
    k_gemm64<<<gb, 256, 0, stream>>>(hB, W3, hA, N);
    k_agg<false><<<ab, 256, 0, stream>>>(hA, dis, row_start, csr, b3, hB, N);

    // pooled mean -> @Wl + bl
    k_pool<<<NGRAPHS, 256, 0, stream>>>(hB, batch, Wl, bl, out, N);
}

// Round 2
// 491.029 us; speedup vs baseline: 1.2683x; 1.2683x over previous
//
#include <hip/hip_runtime.h>

#define NGRAPHS 256
#define NXCD 8

// ---------------- degree / normalization ----------------

__global__ void k_deg(const int* __restrict__ dst, int E, int* __restrict__ deg) {
    int e = blockIdx.x * blockDim.x + threadIdx.x;
    int stride = gridDim.x * blockDim.x;
    for (; e < E; e += stride) atomicAdd(&deg[dst[e]], 1);
}

__global__ void k_dis(const int* __restrict__ deg, float* __restrict__ dis, int N) {
    int i = blockIdx.x * blockDim.x + threadIdx.x;
    if (i < N) dis[i] = rsqrtf((float)deg[i] + 1.0f);
}

// ---------------- exclusive scan (3 kernels) ----------------

__global__ void k_scanA(const int* __restrict__ deg, int N,
                        int* __restrict__ incl, int* __restrict__ bsum) {
    __shared__ int s[256];
    int t = threadIdx.x;
    int i = blockIdx.x * 256 + t;
    int v = (i < N) ? deg[i] : 0;
    s[t] = v;
    __syncthreads();
    for (int o = 1; o < 256; o <<= 1) {
        int add = (t >= o) ? s[t - o] : 0;
        __syncthreads();
        s[t] += add;
        __syncthreads();
    }
    if (i < N) incl[i] = s[t];
    if (t == 255) bsum[blockIdx.x] = s[255];
}

__global__ void k_scanB(int* __restrict__ bsum, int NB) {
    __shared__ int s[512];
    int t = threadIdx.x;
    s[t] = (t < NB) ? bsum[t] : 0;
    __syncthreads();
    for (int o = 1; o < 512; o <<= 1) {
        int add = (t >= o) ? s[t - o] : 0;
        __syncthreads();
        s[t] += add;
        __syncthreads();
    }
    if (t < NB) bsum[t] = (t == 0) ? 0 : s[t - 1];   // exclusive block offsets
}

__global__ void k_scanC(const int* __restrict__ deg, const int* __restrict__ incl,
                        const int* __restrict__ boff, int N, int E,
                        int* __restrict__ row_start, int* __restrict__ cursor) {
    int i = blockIdx.x * 256 + threadIdx.x;
    if (i < N) {
        int ex = incl[i] - deg[i] + boff[blockIdx.x];
        row_start[i] = ex;
        cursor[i] = ex;
    }
    if (i == 0) row_start[N] = E;
}

// XCD-localized scatter: blocks with (blockIdx&7)==g own dst range g.
// Each group streams the full edge list (sequential reads, LLC-resident)
// but writes only its contiguous ~E/8 csr slice -> L2-coalesced writebacks.
__global__ __launch_bounds__(256) void k_scatter(const int* __restrict__ src,
                                                 const int* __restrict__ dst,
                                                 int E, int N,
                                                 int* __restrict__ cursor,
                                                 int* __restrict__ csr_src) {
    int g = blockIdx.x & (NXCD - 1);
    int lo = (int)(((long long)g * N) / NXCD);
    int hi = (int)(((long long)(g + 1) * N) / NXCD);
    int stride = (gridDim.x >> 3) * blockDim.x;
    for (int e = (blockIdx.x >> 3) * blockDim.x + threadIdx.x; e < E; e += stride) {
        int d = dst[e];
        if (d >= lo && d < hi) {
            int pos = atomicAdd(&cursor[d], 1);
            csr_src[pos] = src[e];
        }
    }
}

// ---------------- dense GEMM: G = (X @ W) * dis[row]  (X [N,64], W [64,64]) ----------------

__global__ __launch_bounds__(256) void k_gemm64(const float* __restrict__ X,
                                                const float* __restrict__ W,
                                                const float* __restrict__ dis,
                                                float* __restrict__ G, int N) {
    __shared__ float ws[64 * 64];
    __shared__ float xs[64 * 64];
    int t = threadIdx.x;
    int row0 = blockIdx.x * 64;
    int nr = N - row0; if (nr > 64) nr = 64;

    // stage W (4096 f32 = 1024 float4)
    const float4* W4 = (const float4*)W;
    float4* ws4 = (float4*)ws;
    for (int i = t; i < 1024; i += 256) ws4[i] = W4[i];
    // stage X tile (full rows only)
    const float4* X4 = (const float4*)(X + (size_t)row0 * 64);
    float4* xs4 = (float4*)xs;
    for (int i = t; i < nr * 16; i += 256) xs4[i] = X4[i];
    __syncthreads();

    int col = t & 63;
    int rg  = t >> 6;           // wave id: rows rg*16 .. rg*16+15
    float acc[16];
#pragma unroll
    for (int j = 0; j < 16; ++j) acc[j] = 0.0f;

    for (int k4 = 0; k4 < 16; ++k4) {
        float w0 = ws[(k4 * 4 + 0) * 64 + col];
        float w1 = ws[(k4 * 4 + 1) * 64 + col];
        float w2 = ws[(k4 * 4 + 2) * 64 + col];
        float w3 = ws[(k4 * 4 + 3) * 64 + col];
#pragma unroll
        for (int j = 0; j < 16; ++j) {
            float4 xv = xs4[(rg * 16 + j) * 16 + k4];   // wave-uniform broadcast
            acc[j] = fmaf(xv.x, w0, acc[j]);
            acc[j] = fmaf(xv.y, w1, acc[j]);
            acc[j] = fmaf(xv.z, w2, acc[j]);
            acc[j] = fmaf(xv.w, w3, acc[j]);
        }
    }
#pragma unroll
    for (int j = 0; j < 16; ++j) {
        int r = rg * 16 + j;
        if (r < nr) G[(size_t)(row0 + r) * 64 + col] = acc[j] * dis[row0 + r];
    }
}

// ---------------- aggregation: one wave per node, lane = feature ----------------
// g = h * dis  (prescaled). out_i = dis_i * (sum_{j in N(i)} g_j + g_i) + b, [relu]

template <bool RELU>
__global__ __launch_bounds__(256) void k_agg(const float* __restrict__ g,
                                             const float* __restrict__ dis,
                                             const int* __restrict__ row_start,
                                             const int* __restrict__ csr_src,
                                             const float* __restrict__ b,
                                             float* __restrict__ out, int N) {
    int wid = (blockIdx.x * blockDim.x + threadIdx.x) >> 6;  // node id
    int lane = threadIdx.x & 63;
    if (wid >= N) return;
    int beg = row_start[wid];
    int end = row_start[wid + 1];
    float acc = g[(size_t)wid * 64 + lane];    // self-loop term
    int e = beg;
    for (; e + 4 <= end; e += 4) {
        int s0 = csr_src[e];
        int s1 = csr_src[e + 1];
        int s2 = csr_src[e + 2];
        int s3 = csr_src[e + 3];
        float g0 = g[(size_t)s0 * 64 + lane];
        float g1 = g[(size_t)s1 * 64 + lane];
        float g2 = g[(size_t)s2 * 64 + lane];
        float g3 = g[(size_t)s3 * 64 + lane];
        acc += g0; acc += g1; acc += g2; acc += g3;
    }
    for (; e < end; ++e)
        acc += g[(size_t)csr_src[e] * 64 + lane];
    float v = fmaf(acc, dis[wid], b[lane]);
    if (RELU) v = fmaxf(v, 0.0f);
    out[(size_t)wid * 64 + lane] = v;
}

// ---------------- pooling: block per graph, sorted batch binary search ----------------

__global__ __launch_bounds__(256) void k_pool(const float* __restrict__ h,
                                              const int* __restrict__ batch,
                                              const float* __restrict__ Wl,
                                              const float* __restrict__ bl,
                                              float* __restrict__ out, int N) {
    int g = blockIdx.x;
    int lo = 0, hi = N;
    while (lo < hi) { int m = (lo + hi) >> 1; if (batch[m] < g) lo = m + 1; else hi = m; }
    int start = lo;
    hi = N;
    while (lo < hi) { int m = (lo + hi) >> 1; if (batch[m] <= g) lo = m + 1; else hi = m; }
    int end = lo;

    int lane = threadIdx.x & 63;
    int wv = threadIdx.x >> 6;
    float part = 0.0f;
    for (int i = start + wv; i < end; i += 4)
        part += h[(size_t)i * 64 + lane];
    part *= Wl[lane];
    for (int o = 32; o; o >>= 1) part += __shfl_down(part, o);
    __shared__ float ps[4];
    if (lane == 0) ps[wv] = part;
    __syncthreads();
    if (threadIdx.x == 0) {
        float s = ps[0] + ps[1] + ps[2] + ps[3];
        float cnt = (float)(end - start);
        out[g] = s / fmaxf(cnt, 1.0f) + bl[0];
    }
}

// ---------------- launcher ----------------

extern "C" void kernel_launch(void* const* d_in, const int* in_sizes, int n_in,
                              void* d_out, int out_size, void* d_ws, size_t ws_size,
                              hipStream_t stream) {
    const float* x     = (const float*)d_in[0];
    const int*   ei    = (const int*)d_in[1];
    const int*   batch = (const int*)d_in[2];
    const float* W1 = (const float*)d_in[3];
    const float* b1 = (const float*)d_in[4];
    const float* W2 = (const float*)d_in[5];
    const float* b2 = (const float*)d_in[6];
    const float* W3 = (const float*)d_in[7];
    const float* b3 = (const float*)d_in[8];
    const float* Wl = (const float*)d_in[9];
    const float* bl = (const float*)d_in[10];
    float* out = (float*)d_out;

    const int N = in_sizes[0] / 64;
    const int E = in_sizes[1] / 2;
    const int* src = ei;
    const int* dst = ei + E;

    char* w = (char*)d_ws;
    auto alloc = [&](size_t bytes) -> void* {
        void* p = (void*)w;
        w += (bytes + 255) & ~(size_t)255;
        return p;
    };
    float* hA        = (float*)alloc((size_t)N * 64 * 4);
    float* hB        = (float*)alloc((size_t)N * 64 * 4);
    int*   csr       = (int*)alloc((size_t)E * 4);
    int*   deg       = (int*)alloc((size_t)N * 4);
    float* dis       = (float*)alloc((size_t)N * 4);
    int*   incl      = (int*)alloc((size_t)N * 4);
    int*   row_start = (int*)alloc((size_t)(N + 1) * 4);
    int*   cursor    = (int*)alloc((size_t)N * 4);
    int*   bsum      = (int*)alloc((size_t)512 * 4);

    hipMemsetAsync(deg, 0, (size_t)N * 4, stream);

    int eb = (E + 255) / 256; if (eb > 2048) eb = 2048;
    int nb = (N + 255) / 256;   // 391 for N=100000, fits k_scanB's 512

    k_deg<<<eb, 256, 0, stream>>>(dst, E, deg);
    k_dis<<<nb, 256, 0, stream>>>(deg, dis, N);
    k_scanA<<<nb, 256, 0, stream>>>(deg, N, incl, bsum);
    k_scanB<<<1, 512, 0, stream>>>(bsum, nb);
    k_scanC<<<nb, 256, 0, stream>>>(deg, incl, bsum, N, E, row_start, cursor);
    k_scatter<<<2048, 256, 0, stream>>>(src, dst, E, N, cursor, csr);

    int gb = (N + 63) / 64;     // gemm blocks
    int ab = (N + 3) / 4;       // agg blocks (4 waves/block, wave per node)

    // layer 1: relu(gcn(x, W1, b1))
    k_gemm64<<<gb, 256, 0, stream>>>(x, W1, dis, hA, N);
    k_agg<true><<<ab, 256, 0, stream>>>(hA, dis, row_start, csr, b1, hB, N);
    // layer 2
    k_gemm64<<<gb, 256, 0, stream>>>(hB, W2, dis, hA, N);
    k_agg<true><<<ab, 256, 0, stream>>>(hA, dis, row_start, csr, b2, hB, N);
    // layer 3 (no relu)
    k_gemm64<<<gb, 256, 0, stream>>>(hB, W3, dis, hA, N);
    k_agg<false><<<ab, 256, 0, stream>>>(hA, dis, row_start, csr, b3, hB, N);

    // pooled mean -> @Wl + bl
    k_pool<<<NGRAPHS, 256, 0, stream>>>(hB, batch, Wl, bl, out, N);
}

// Round 3
// 465.554 us; speedup vs baseline: 1.3377x; 1.0547x over previous
//
#include <hip/hip_runtime.h>

#define NGRAPHS 256
#define NXCD 8

// ---------------- degree / normalization ----------------

__global__ void k_deg(const int* __restrict__ dst, int E, int* __restrict__ deg) {
    int e = blockIdx.x * blockDim.x + threadIdx.x;
    int stride = gridDim.x * blockDim.x;
    for (; e < E; e += stride) atomicAdd(&deg[dst[e]], 1);
}

__global__ void k_dis(const int* __restrict__ deg, float* __restrict__ dis, int N) {
    int i = blockIdx.x * blockDim.x + threadIdx.x;
    if (i < N) dis[i] = rsqrtf((float)deg[i] + 1.0f);
}

// ---------------- exclusive scan (3 kernels) ----------------

__global__ void k_scanA(const int* __restrict__ deg, int N,
                        int* __restrict__ incl, int* __restrict__ bsum) {
    __shared__ int s[256];
    int t = threadIdx.x;
    int i = blockIdx.x * 256 + t;
    int v = (i < N) ? deg[i] : 0;
    s[t] = v;
    __syncthreads();
    for (int o = 1; o < 256; o <<= 1) {
        int add = (t >= o) ? s[t - o] : 0;
        __syncthreads();
        s[t] += add;
        __syncthreads();
    }
    if (i < N) incl[i] = s[t];
    if (t == 255) bsum[blockIdx.x] = s[255];
}

__global__ void k_scanB(int* __restrict__ bsum, int NB) {
    __shared__ int s[512];
    int t = threadIdx.x;
    s[t] = (t < NB) ? bsum[t] : 0;
    __syncthreads();
    for (int o = 1; o < 512; o <<= 1) {
        int add = (t >= o) ? s[t - o] : 0;
        __syncthreads();
        s[t] += add;
        __syncthreads();
    }
    if (t < NB) bsum[t] = (t == 0) ? 0 : s[t - 1];   // exclusive block offsets
}

__global__ void k_scanC(const int* __restrict__ deg, const int* __restrict__ incl,
                        const int* __restrict__ boff, int N, int E,
                        int* __restrict__ row_start, int* __restrict__ cursor) {
    int i = blockIdx.x * 256 + threadIdx.x;
    if (i < N) {
        int ex = incl[i] - deg[i] + boff[blockIdx.x];
        row_start[i] = ex;
        cursor[i] = ex;
    }
    if (i == 0) row_start[N] = E;
}

// XCD-localized scatter: blocks with (blockIdx&7)==g own dst range g.
__global__ __launch_bounds__(256) void k_scatter(const int* __restrict__ src,
                                                 const int* __restrict__ dst,
                                                 int E, int N,
                                                 int* __restrict__ cursor,
                                                 int* __restrict__ csr_src) {
    int g = blockIdx.x & (NXCD - 1);
    int lo = (int)(((long long)g * N) / NXCD);
    int hi = (int)(((long long)(g + 1) * N) / NXCD);
    int stride = (gridDim.x >> 3) * blockDim.x;
    for (int e = (blockIdx.x >> 3) * blockDim.x + threadIdx.x; e < E; e += stride) {
        int d = dst[e];
        if (d >= lo && d < hi) {
            int pos = atomicAdd(&cursor[d], 1);
            csr_src[pos] = src[e];
        }
    }
}

// ---------------- dense GEMM: G = (X @ W) * dis[row]  (X [N,64], W [64,64]) ----------------

__global__ __launch_bounds__(256) void k_gemm64(const float* __restrict__ X,
                                                const float* __restrict__ W,
                                                const float* __restrict__ dis,
                                                float* __restrict__ G, int N) {
    __shared__ float ws[64 * 64];
    __shared__ float xs[64 * 64];
    int t = threadIdx.x;
    int row0 = blockIdx.x * 64;
    int nr = N - row0; if (nr > 64) nr = 64;

    const float4* W4 = (const float4*)W;
    float4* ws4 = (float4*)ws;
    for (int i = t; i < 1024; i += 256) ws4[i] = W4[i];
    const float4* X4 = (const float4*)(X + (size_t)row0 * 64);
    float4* xs4 = (float4*)xs;
    for (int i = t; i < nr * 16; i += 256) xs4[i] = X4[i];
    __syncthreads();

    int col = t & 63;
    int rg  = t >> 6;
    float acc[16];
#pragma unroll
    for (int j = 0; j < 16; ++j) acc[j] = 0.0f;

    for (int k4 = 0; k4 < 16; ++k4) {
        float w0 = ws[(k4 * 4 + 0) * 64 + col];
        float w1 = ws[(k4 * 4 + 1) * 64 + col];
        float w2 = ws[(k4 * 4 + 2) * 64 + col];
        float w3 = ws[(k4 * 4 + 3) * 64 + col];
#pragma unroll
        for (int j = 0; j < 16; ++j) {
            float4 xv = xs4[(rg * 16 + j) * 16 + k4];
            acc[j] = fmaf(xv.x, w0, acc[j]);
            acc[j] = fmaf(xv.y, w1, acc[j]);
            acc[j] = fmaf(xv.z, w2, acc[j]);
            acc[j] = fmaf(xv.w, w3, acc[j]);
        }
    }
#pragma unroll
    for (int j = 0; j < 16; ++j) {
        int r = rg * 16 + j;
        if (r < nr) G[(size_t)(row0 + r) * 64 + col] = acc[j] * dis[row0 + r];
    }
}

// ---------------- aggregation: one wave per node, 4 edges in parallel ----------------
// g prescaled by dis.  out_i = dis_i * (sum_{j in N(i)} g_j + g_i) + b, [relu]
// lane = 16*sub + q : sub in 0..3 = edge slot, q in 0..15 = float4 chunk of row.
// One dwordx4 load per trip fetches 4 rows (1 KB); x2 unroll = 8 edges in flight.

template <bool RELU>
__global__ __launch_bounds__(256) void k_agg(const float* __restrict__ g,
                                             const float* __restrict__ dis,
                                             const int* __restrict__ row_start,
                                             const int* __restrict__ csr_src,
                                             const float* __restrict__ b,
                                             float* __restrict__ out, int N) {
    int wid = (blockIdx.x * blockDim.x + threadIdx.x) >> 6;  // node id
    if (wid >= N) return;
    int lane = threadIdx.x & 63;
    int sub  = lane >> 4;       // edge slot 0..3
    int q    = lane & 15;       // float4 chunk 0..15

    const float4* g4 = (const float4*)g;
    int beg = row_start[wid];
    int end = row_start[wid + 1];

    float4 acc;
    if (sub == 0) acc = g4[(size_t)wid * 16 + q];   // self-loop term, added once
    else          acc = make_float4(0.f, 0.f, 0.f, 0.f);

    int e = beg;
    for (; e + 8 <= end; e += 8) {
        int sA = csr_src[e + sub];
        int sB = csr_src[e + 4 + sub];
        float4 a = g4[(size_t)sA * 16 + q];
        float4 c = g4[(size_t)sB * 16 + q];
        acc.x += a.x; acc.y += a.y; acc.z += a.z; acc.w += a.w;
        acc.x += c.x; acc.y += c.y; acc.z += c.z; acc.w += c.w;
    }
    if (e + 4 <= end) {
        int sA = csr_src[e + sub];
        float4 a = g4[(size_t)sA * 16 + q];
        acc.x += a.x; acc.y += a.y; acc.z += a.z; acc.w += a.w;
        e += 4;
    }
    int rem = end - e;           // 0..3
    if (sub < rem) {
        int sA = csr_src[e + sub];
        float4 a = g4[(size_t)sA * 16 + q];
        acc.x += a.x; acc.y += a.y; acc.z += a.z; acc.w += a.w;
    }

    // reduce across the 4 edge slots (lanes differing in bits 4,5)
#pragma unroll
    for (int o = 16; o <= 32; o <<= 1) {
        acc.x += __shfl_xor(acc.x, o);
        acc.y += __shfl_xor(acc.y, o);
        acc.z += __shfl_xor(acc.z, o);
        acc.w += __shfl_xor(acc.w, o);
    }

    if (sub == 0) {
        float d = dis[wid];
        float4 bv = ((const float4*)b)[q];
        float4 v;
        v.x = fmaf(acc.x, d, bv.x);
        v.y = fmaf(acc.y, d, bv.y);
        v.z = fmaf(acc.z, d, bv.z);
        v.w = fmaf(acc.w, d, bv.w);
        if (RELU) {
            v.x = fmaxf(v.x, 0.f); v.y = fmaxf(v.y, 0.f);
            v.z = fmaxf(v.z, 0.f); v.w = fmaxf(v.w, 0.f);
        }
        ((float4*)out)[(size_t)wid * 16 + q] = v;
    }
}

// ---------------- pooling: block per graph, sorted batch binary search ----------------

__global__ __launch_bounds__(256) void k_pool(const float* __restrict__ h,
                                              const int* __restrict__ batch,
                                              const float* __restrict__ Wl,
                                              const float* __restrict__ bl,
                                              float* __restrict__ out, int N) {
    int g = blockIdx.x;
    int lo = 0, hi = N;
    while (lo < hi) { int m = (lo + hi) >> 1; if (batch[m] < g) lo = m + 1; else hi = m; }
    int start = lo;
    hi = N;
    while (lo < hi) { int m = (lo + hi) >> 1; if (batch[m] <= g) lo = m + 1; else hi = m; }
    int end = lo;

    int lane = threadIdx.x & 63;
    int wv = threadIdx.x >> 6;
    float part = 0.0f;
    for (int i = start + wv; i < end; i += 4)
        part += h[(size_t)i * 64 + lane];
    part *= Wl[lane];
    for (int o = 32; o; o >>= 1) part += __shfl_down(part, o);
    __shared__ float ps[4];
    if (lane == 0) ps[wv] = part;
    __syncthreads();
    if (threadIdx.x == 0) {
        float s = ps[0] + ps[1] + ps[2] + ps[3];
        float cnt = (float)(end - start);
        out[g] = s / fmaxf(cnt, 1.0f) + bl[0];
    }
}

// ---------------- launcher ----------------

extern "C" void kernel_launch(void* const* d_in, const int* in_sizes, int n_in,
                              void* d_out, int out_size, void* d_ws, size_t ws_size,
                              hipStream_t stream) {
    const float* x     = (const float*)d_in[0];
    const int*   ei    = (const int*)d_in[1];
    const int*   batch = (const int*)d_in[2];
    const float* W1 = (const float*)d_in[3];
    const float* b1 = (const float*)d_in[4];
    const float* W2 = (const float*)d_in[5];
    const float* b2 = (const float*)d_in[6];
    const float* W3 = (const float*)d_in[7];
    const float* b3 = (const float*)d_in[8];
    const float* Wl = (const float*)d_in[9];
    const float* bl = (const float*)d_in[10];
    float* out = (float*)d_out;

    const int N = in_sizes[0] / 64;
    const int E = in_sizes[1] / 2;
    const int* src = ei;
    const int* dst = ei + E;

    char* w = (char*)d_ws;
    auto alloc = [&](size_t bytes) -> void* {
        void* p = (void*)w;
        w += (bytes + 255) & ~(size_t)255;
        return p;
    };
    float* hA        = (float*)alloc((size_t)N * 64 * 4);
    float* hB        = (float*)alloc((size_t)N * 64 * 4);
    int*   csr       = (int*)alloc((size_t)E * 4);
    int*   deg       = (int*)alloc((size_t)N * 4);
    float* dis       = (float*)alloc((size_t)N * 4);
    int*   incl      = (int*)alloc((size_t)N * 4);
    int*   row_start = (int*)alloc((size_t)(N + 1) * 4);
    int*   cursor    = (int*)alloc((size_t)N * 4);
    int*   bsum      = (int*)alloc((size_t)512 * 4);

    hipMemsetAsync(deg, 0, (size_t)N * 4, stream);

    int eb = (E + 255) / 256; if (eb > 2048) eb = 2048;
    int nb = (N + 255) / 256;   // 391 for N=100000, fits k_scanB's 512

    k_deg<<<eb, 256, 0, stream>>>(dst, E, deg);
    k_dis<<<nb, 256, 0, stream>>>(deg, dis, N);
    k_scanA<<<nb, 256, 0, stream>>>(deg, N, incl, bsum);
    k_scanB<<<1, 512, 0, stream>>>(bsum, nb);
    k_scanC<<<nb, 256, 0, stream>>>(deg, incl, bsum, N, E, row_start, cursor);
    k_scatter<<<2048, 256, 0, stream>>>(src, dst, E, N, cursor, csr);

    int gb = (N + 63) / 64;     // gemm blocks
    int ab = (N + 3) / 4;       // agg blocks (4 waves/block, wave per node)

    // layer 1: relu(gcn(x, W1, b1))
    k_gemm64<<<gb, 256, 0, stream>>>(x, W1, dis, hA, N);
    k_agg<true><<<ab, 256, 0, stream>>>(hA, dis, row_start, csr, b1, hB, N);
    // layer 2
    k_gemm64<<<gb, 256, 0, stream>>>(hB, W2, dis, hA, N);
    k_agg<true><<<ab, 256, 0, stream>>>(hA, dis, row_start, csr, b2, hB, N);
    // layer 3 (no relu)
    k_gemm64<<<gb, 256, 0, stream>>>(hB, W3, dis, hA, N);
    k_agg<false><<<ab, 256, 0, stream>>>(hA, dis, row_start, csr, b3, hB, N);

    // pooled mean -> @Wl + bl
    k_pool<<<NGRAPHS, 256, 0, stream>>>(hB, batch, Wl, bl, out, N);
}